// Round 11
// baseline (337.468 us; speedup 1.0000x reference)
//
#include <hip/hip_runtime.h>

#define NPTS   8192
#define CCH    32
#define LDIM   64
#define ODIM   128
#define KNN    16
#define QPB    64                  // queries per block (16 per wave = MFMA tile rows)
#define TILEC  128
#define NTIL   (NPTS / TILEC)      // 64
#define NBLK   ((4 * NPTS) / QPB)  // 512 blocks (grid-limited: 2 blocks/CU)
#define SCAP   56                  // survivor capacity per query
#define MARGIN 0.75f               // >= 2*eps bound for fp16 distance error

typedef _Float16 half8   __attribute__((ext_vector_type(8)));
typedef float    float4v __attribute__((ext_vector_type(4)));

// Prologue A: fp32 -> fp16 rows (64B) + exact fp32 squared norms.
__global__ void prep_kernel(const float* __restrict__ x, _Float16* __restrict__ xh,
                            float* __restrict__ sqg) {
    int i = blockIdx.x * 256 + threadIdx.x;    // one point row per thread
    const float4* p = (const float4*)(x + (size_t)i * CCH);
    float s = 0.f;
    half8 h[4];
    #pragma unroll
    for (int k = 0; k < 8; ++k) {
        float4 v = p[k];
        s += v.x*v.x + v.y*v.y + v.z*v.z + v.w*v.w;
        h[k >> 1][(k & 1) * 4 + 0] = (_Float16)v.x;
        h[k >> 1][(k & 1) * 4 + 1] = (_Float16)v.y;
        h[k >> 1][(k & 1) * 4 + 2] = (_Float16)v.z;
        h[k >> 1][(k & 1) * 4 + 3] = (_Float16)v.w;
    }
    half8* dst = (half8*)(xh + (size_t)i * CCH);
    dst[0] = h[0]; dst[1] = h[1]; dst[2] = h[2]; dst[3] = h[3];
    sqg[i] = s;
}

// Prologue B (fallback when ws too small for xh): sq only.
__global__ void sq_kernel(const float* __restrict__ x, float* __restrict__ sqg) {
    int i = blockIdx.x * 256 + threadIdx.x;
    const float4* p = (const float4*)(x + (size_t)i * CCH);
    float s = 0.f;
    #pragma unroll
    for (int k = 0; k < 8; ++k) {
        float4 v = p[k];
        s += v.x*v.x + v.y*v.y + v.z*v.z + v.w*v.w;
    }
    sqg[i] = s;
}

// LDS (phase overlays; NO LDS in the scan loops):
//  slist @0 (14336) [t32 overlay @0 (8192) during threshold phase]
//  skeys @14336 (14336) | scnt @28672 (256) | tq @28928 (256) | kn @29184 (4096)
//  epilogue: pl @0 (8448) | hh @8448 (16640)   (kn @29184 stays live)
#define LDS_BYTES 33280
#define OFF_SK 14336
#define OFF_SC 28672
#define OFF_TQ 28928
#define OFF_KN 29184
#define OFF_HH 8448

// (256,2): grid is 512 blocks = 2 blocks/CU, so occupancy is grid-limited;
// claiming more waves/EU only caps VGPRs and causes spill (r10: WRITE 16->42MB).
template<bool PRECVT>
__global__ __launch_bounds__(256, 2)
void graph_layer_kernel(const float* __restrict__ x,
                        const _Float16* __restrict__ xh,
                        const float* __restrict__ sqg,
                        const float* __restrict__ Wl,
                        const float* __restrict__ bl,
                        const float* __restrict__ Wc,
                        const float* __restrict__ bc,
                        float* __restrict__ out)
{
    __shared__ __align__(16) char smem[LDS_BYTES];
    int*   slist = (int*)smem;
    float* t32   = (float*)smem;               // overlay, consumed before slist writes
    float* skeys = (float*)(smem + OFF_SK);
    int*   scnt  = (int*)(smem + OFF_SC);
    float* tq    = (float*)(smem + OFF_TQ);
    int*   kn    = (int*)(smem + OFF_KN);
    float* pl    = (float*)smem;               // epilogue overlay
    float* hh    = (float*)(smem + OFF_HH);

    const int tid  = threadIdx.x;
    const int lane = tid & 63;
    const int w    = tid >> 6;
    const int col  = lane & 15;                // candidate column / A-frag row
    const int quad = lane >> 4;
    const float INF = __builtin_inff();

    const int qb0 = blockIdx.x * QPB;
    const int b   = qb0 >> 13;
    const int qbl = qb0 & (NPTS - 1);
    const float* xb  = x + (size_t)(b << 13) * CCH;
    const _Float16* xhb = PRECVT ? (xh + (size_t)(b << 13) * CCH) : nullptr;
    const float* sqb = sqg + (b << 13);

    // ---- A-fragment: wave's 16 queries in fp16; A[m=col][k=quad*8+j] ----
    half8 qh;
    {
        const float* qr = x + (size_t)(qb0 + w * 16 + col) * CCH + quad * 8;
        float4 f0 = *(const float4*)qr;
        float4 f1 = *(const float4*)(qr + 4);
        qh[0]=(_Float16)f0.x; qh[1]=(_Float16)f0.y; qh[2]=(_Float16)f0.z; qh[3]=(_Float16)f0.w;
        qh[4]=(_Float16)f1.x; qh[5]=(_Float16)f1.y; qh[6]=(_Float16)f1.z; qh[7]=(_Float16)f1.w;
    }

    auto load_bh = [&](int cand) -> half8 {
        if (PRECVT) {
            return *(const half8*)(xhb + (size_t)cand * CCH + quad * 8);
        } else {
            const float4* cp = (const float4*)(xb + (size_t)cand * CCH + quad * 8);
            float4 f0 = cp[0], f1 = cp[1];
            half8 bh;
            bh[0]=(_Float16)f0.x; bh[1]=(_Float16)f0.y; bh[2]=(_Float16)f0.z; bh[3]=(_Float16)f0.w;
            bh[4]=(_Float16)f1.x; bh[5]=(_Float16)f1.y; bh[6]=(_Float16)f1.z; bh[7]=(_Float16)f1.w;
            return bh;
        }
    };

    // ================= PASS 1: branch-free per-lane top-2 per query ==========
    // no LDS, no barriers: direct global->VGPR B-fragments (L1/L2-resident)
    float m1[4] = {INF, INF, INF, INF};
    float m2[4] = {INF, INF, INF, INF};
    #pragma unroll 1
    for (int T = 0; T < NTIL; ++T) {
        const int cb = T * TILEC;
        #pragma unroll
        for (int st = 0; st < 8; ++st) {
            const int cand = cb + st * 16 + col;
            half8 bh = load_bh(cand);
            float sc = sqb[cand];
            float4v acc = __builtin_amdgcn_mfma_f32_16x16x32_f16(
                qh, bh, (float4v){0.f, 0.f, 0.f, 0.f}, 0, 0, 0);
            #pragma unroll
            for (int j = 0; j < 4; ++j) {
                float key = fmaf(-2.f, acc[j], sc);
                // sorted top-2 insert in 2 ops: med3 + min
                m2[j] = __builtin_amdgcn_fmed3f(key, m1[j], m2[j]);
                m1[j] = fminf(key, m1[j]);
            }
        }
    }

    // ---- per-query threshold: 16th smallest of the 32-value union ----
    #pragma unroll
    for (int j = 0; j < 4; ++j) {
        int qq = w * 16 + quad * 4 + j;
        t32[qq * 32 + col * 2 + 0] = m1[j];
        t32[qq * 32 + col * 2 + 1] = m2[j];
    }
    __syncthreads();
    if (tid < QPB) {
        float kd[KNN];
        #pragma unroll
        for (int p = 0; p < KNN; ++p) kd[p] = INF;
        for (int i = 0; i < 32; ++i) {
            float ck = t32[tid * 32 + i];
            if (ck < kd[KNN - 1]) {
                #pragma unroll
                for (int p = 0; p < KNN; ++p) {
                    bool sw = ck < kd[p];
                    float nk = sw ? ck : kd[p];
                    ck = sw ? kd[p] : ck;
                    kd[p] = nk;
                }
            }
        }
        tq[tid] = kd[KNN - 1];
        scnt[tid] = 0;
    }
    __syncthreads();
    float T2[4];
    #pragma unroll
    for (int j = 0; j < 4; ++j) T2[j] = tq[w * 16 + quad * 4 + j] + MARGIN;

    // ================= PASS 2: rescan, atomic survivor append ==========
    #pragma unroll 1
    for (int T = 0; T < NTIL; ++T) {
        const int cb = T * TILEC;
        #pragma unroll
        for (int st = 0; st < 8; ++st) {
            const int cand = cb + st * 16 + col;
            half8 bh = load_bh(cand);
            float sc = sqb[cand];
            float4v acc = __builtin_amdgcn_mfma_f32_16x16x32_f16(
                qh, bh, (float4v){0.f, 0.f, 0.f, 0.f}, 0, 0, 0);
            #pragma unroll
            for (int j = 0; j < 4; ++j) {
                float key = fmaf(-2.f, acc[j], sc);
                if (key < T2[j]) {
                    int qq = w * 16 + quad * 4 + j;
                    int slot = atomicAdd(&scnt[qq], 1);
                    if (slot < SCAP)
                        slist[qq * SCAP + slot] = cand;
                }
            }
        }
    }
    __syncthreads();

    // ================= PASS 3: exact fp32 re-check of survivors ==========
    {
        int qq = tid & 63, sb = tid >> 6;
        int n = scnt[qq]; if (n > SCAP) n = SCAP;
        const float4* xi4 = (const float4*)(xb + (size_t)(qbl + qq) * CCH);
        for (int s = sb; s < n; s += 4) {
            int jdx = slist[qq * SCAP + s];
            const float4* xj = (const float4*)(xb + (size_t)jdx * CCH);
            float a0 = 0.f, a1 = 0.f, a2 = 0.f, a3 = 0.f;
            #pragma unroll
            for (int k = 0; k < 8; ++k) {
                float4 cv = xj[k], qv = xi4[k];
                a0 = fmaf(cv.x, qv.x, a0); a1 = fmaf(cv.y, qv.y, a1);
                a2 = fmaf(cv.z, qv.z, a2); a3 = fmaf(cv.w, qv.w, a3);
            }
            float dot = (a0 + a1) + (a2 + a3);
            skeys[qq * SCAP + s] = fmaf(-2.f, dot, sqb[jdx]);
        }
    }
    __syncthreads();
    if (tid < QPB) {      // exact (key, idx) top-16; slist unordered -> full lex compare
        int n = scnt[tid]; if (n > SCAP) n = SCAP;
        float kd[KNN]; int ki[KNN];
        #pragma unroll
        for (int p = 0; p < KNN; ++p) { kd[p] = INF; ki[p] = 0x7fffffff; }
        for (int s = 0; s < n; ++s) {
            float ck = skeys[tid * SCAP + s];
            int   cj = slist[tid * SCAP + s];
            if (ck < kd[KNN-1] || (ck == kd[KNN-1] && cj < ki[KNN-1])) {
                #pragma unroll
                for (int p = 0; p < KNN; ++p) {
                    bool sw = (ck < kd[p]) || (ck == kd[p] && cj < ki[p]);
                    float nk = sw ? ck : kd[p];
                    int   nj = sw ? cj : ki[p];
                    ck = sw ? kd[p] : ck;
                    cj = sw ? ki[p] : cj;
                    kd[p] = nk; ki[p] = nj;
                }
            }
        }
        #pragma unroll
        for (int r = 0; r < KNN; ++r) kn[tid * KNN + r] = ki[r];
    }
    __syncthreads();

    // ================= epilogue: gather + max-pool + MLP ==========
    {
        int q = tid >> 2, part = tid & 3;
        float4 m0 = make_float4(-INF, -INF, -INF, -INF);
        float4 mm1 = m0;
        #pragma unroll
        for (int k = 0; k < KNN; ++k) {
            int j = kn[q * KNN + k];
            const float4* r = (const float4*)(xb + (size_t)j * CCH + part * 8);
            float4 v0 = r[0], v1 = r[1];
            m0.x = fmaxf(m0.x, v0.x); m0.y = fmaxf(m0.y, v0.y);
            m0.z = fmaxf(m0.z, v0.z); m0.w = fmaxf(m0.w, v0.w);
            mm1.x = fmaxf(mm1.x, v1.x); mm1.y = fmaxf(mm1.y, v1.y);
            mm1.z = fmaxf(mm1.z, v1.z); mm1.w = fmaxf(mm1.w, v1.w);
        }
        float* d = pl + q * 33 + part * 8;
        d[0] = m0.x; d[1] = m0.y; d[2] = m0.z; d[3] = m0.w;
        d[4] = mm1.x; d[5] = mm1.y; d[6] = mm1.z; d[7] = mm1.w;
    }
    __syncthreads();
    {
        int l = tid & 63, qg2 = tid >> 6;
        #pragma unroll 1
        for (int qq = qg2; qq < QPB; qq += 4) {
            float acc = bl[l];
            #pragma unroll
            for (int c = 0; c < CCH; ++c)
                acc = fmaf(pl[qq * 33 + c], Wl[c * LDIM + l], acc);
            hh[qq * 65 + l] = acc;
        }
    }
    __syncthreads();
    {
        int o = tid & 127, qh2 = tid >> 7;
        #pragma unroll 1
        for (int qq = qh2; qq < QPB; qq += 2) {
            float acc = bc[o];
            #pragma unroll
            for (int l = 0; l < LDIM; ++l)
                acc = fmaf(hh[qq * 65 + l], Wc[l * ODIM + o], acc);
            out[(size_t)(qb0 + qq) * ODIM + o] = fmaxf(acc, 0.f);
        }
    }
}

extern "C" void kernel_launch(void* const* d_in, const int* in_sizes, int n_in,
                              void* d_out, int out_size, void* d_ws, size_t ws_size,
                              hipStream_t stream) {
    const float* x  = (const float*)d_in[0];
    const float* Wl = (const float*)d_in[1];
    const float* bl = (const float*)d_in[2];
    const float* Wc = (const float*)d_in[3];
    const float* bc = (const float*)d_in[4];
    float* out = (float*)d_out;
    (void)in_sizes; (void)n_in; (void)out_size;

    const size_t npts_total = (size_t)4 * NPTS;
    const size_t xh_bytes = npts_total * CCH * sizeof(_Float16);   // 2 MB
    const size_t need = xh_bytes + npts_total * sizeof(float);     // + 128 KB

    if (ws_size >= need) {
        _Float16* xhp = (_Float16*)d_ws;
        float* sqf = (float*)((char*)d_ws + xh_bytes);
        hipLaunchKernelGGL(prep_kernel, dim3(npts_total / 256), dim3(256), 0, stream,
                           x, xhp, sqf);
        hipLaunchKernelGGL((graph_layer_kernel<true>), dim3(NBLK), dim3(256), 0, stream,
                           x, xhp, sqf, Wl, bl, Wc, bc, out);
    } else {
        float* sqf = (float*)d_ws;
        hipLaunchKernelGGL(sq_kernel, dim3(npts_total / 256), dim3(256), 0, stream,
                           x, sqf);
        hipLaunchKernelGGL((graph_layer_kernel<false>), dim3(NBLK), dim3(256), 0, stream,
                           x, (const _Float16*)nullptr, sqf, Wl, bl, Wc, bc, out);
    }
}